// Round 2
// baseline (384.049 us; speedup 1.0000x reference)
//
#include <hip/hip_runtime.h>
#include <hip/hip_bf16.h>

// FacePartGAT: dense-graph GATConv x2 + mean + fc on MI355X. ALL I/O fp32.
// Key trick: e[i,j] = leaky_relu(t_i + s_j) => softmax aggregation factorizes
// after sorting sources by s_j:
//   out_i = (e^{t_i} SS[k_i] + e^{0.2 t_i} PP[k_i]) / (e^{t_i} zS[k_i] + e^{0.2 t_i} zP[k_i])
// SS/PP suffix/prefix sums over sorted rank, k_i = lower_bound(sortedS, -t_i).
// Exact (reordered summation) — avoids the O(N^2 C) dense aggregation.

#define NNODE 4096
#define CDIM 128
#define NEG 0.2f
#define CHUNK 64
#define NCHUNK 64  // NNODE / CHUNK

// C[M,Nn] = A[M,K] * B[K,Nn], all fp32. 64x64 tile, K-chunk 32, 256 thr, 4x4/thr.
__global__ __launch_bounds__(256) void gemm_tile(const float* __restrict__ A,
                                                 const float* __restrict__ B,
                                                 float* __restrict__ Cm,
                                                 int M, int Nn, int K) {
  __shared__ float As[32][65];
  __shared__ float Bs[32][65];
  int tid = threadIdx.x;
  int tx = tid & 15, ty = tid >> 4;
  int n0 = blockIdx.x * 64, m0 = blockIdx.y * 64;
  int am = tid >> 2, aq = tid & 3;  // A: row am (64), k-octet aq (4)
  int bk = tid >> 3, bc = tid & 7;  // B: k-row bk (32), n-octet bc (8)
  float acc[4][4] = {};
  for (int k0 = 0; k0 < K; k0 += 32) {
    const float4* pa = (const float4*)(A + (size_t)(m0 + am) * K + k0 + aq * 8);
    float4 a0 = pa[0], a1 = pa[1];
    As[aq * 8 + 0][am] = a0.x; As[aq * 8 + 1][am] = a0.y;
    As[aq * 8 + 2][am] = a0.z; As[aq * 8 + 3][am] = a0.w;
    As[aq * 8 + 4][am] = a1.x; As[aq * 8 + 5][am] = a1.y;
    As[aq * 8 + 6][am] = a1.z; As[aq * 8 + 7][am] = a1.w;
    const float4* pb = (const float4*)(B + (size_t)(k0 + bk) * Nn + n0 + bc * 8);
    float4 b0 = pb[0], b1 = pb[1];
    Bs[bk][bc * 8 + 0] = b0.x; Bs[bk][bc * 8 + 1] = b0.y;
    Bs[bk][bc * 8 + 2] = b0.z; Bs[bk][bc * 8 + 3] = b0.w;
    Bs[bk][bc * 8 + 4] = b1.x; Bs[bk][bc * 8 + 5] = b1.y;
    Bs[bk][bc * 8 + 6] = b1.z; Bs[bk][bc * 8 + 7] = b1.w;
    __syncthreads();
#pragma unroll 8
    for (int kk = 0; kk < 32; kk++) {
      float av[4], bv[4];
#pragma unroll
      for (int i = 0; i < 4; i++) av[i] = As[kk][ty * 4 + i];
#pragma unroll
      for (int j = 0; j < 4; j++) bv[j] = Bs[kk][tx * 4 + j];
#pragma unroll
      for (int i = 0; i < 4; i++)
#pragma unroll
        for (int j = 0; j < 4; j++) acc[i][j] = fmaf(av[i], bv[j], acc[i][j]);
    }
    __syncthreads();
  }
#pragma unroll
  for (int i = 0; i < 4; i++)
#pragma unroll
    for (int j = 0; j < 4; j++)
      Cm[(size_t)(m0 + ty * 4 + i) * Nn + n0 + tx * 4 + j] = acc[i][j];
}

// s[h][n] = sum_c h[n, h*C+c] * att_src[h*C+c]; t likewise with att_dst.
__global__ __launch_bounds__(128) void st_kernel(const float* __restrict__ h,
                                                 const float* __restrict__ asrc,
                                                 const float* __restrict__ adst,
                                                 float* __restrict__ s, float* __restrict__ t,
                                                 int H) {
  __shared__ float red[128];
  int n = blockIdx.x, tid = threadIdx.x;
  int HC = H * CDIM;
  for (int hh = 0; hh < H; hh++) {
    float v = h[(size_t)n * HC + hh * CDIM + tid];
    float ps = v * asrc[hh * CDIM + tid];
    float pt = v * adst[hh * CDIM + tid];
    red[tid] = ps; __syncthreads();
    for (int o = 64; o > 0; o >>= 1) { if (tid < o) red[tid] += red[tid + o]; __syncthreads(); }
    if (tid == 0) s[(size_t)hh * NNODE + n] = red[0];
    __syncthreads();
    red[tid] = pt; __syncthreads();
    for (int o = 64; o > 0; o >>= 1) { if (tid < o) red[tid] += red[tid + o]; __syncthreads(); }
    if (tid == 0) t[(size_t)hh * NNODE + n] = red[0];
    __syncthreads();
  }
}

// Bitonic sort of 4096 (key,idx) pairs per head, ascending. One block per head.
__global__ __launch_bounds__(1024) void sort_kernel(const float* __restrict__ s,
                                                    float* __restrict__ ss,
                                                    int* __restrict__ si) {
  __shared__ float key[NNODE];
  __shared__ int idx[NNODE];
  int h = blockIdx.x, tid = threadIdx.x;
  for (int k = tid; k < NNODE; k += 1024) { key[k] = s[(size_t)h * NNODE + k]; idx[k] = k; }
  for (int size = 2; size <= NNODE; size <<= 1) {
    for (int stride = size >> 1; stride > 0; stride >>= 1) {
      __syncthreads();
      for (int t = tid; t < NNODE / 2; t += 1024) {
        int i = 2 * t - (t & (stride - 1));
        int j = i + stride;
        bool asc = ((i & size) == 0);
        float ki = key[i], kj = key[j];
        if ((ki > kj) == asc) {
          key[i] = kj; key[j] = ki;
          int tmp = idx[i]; idx[i] = idx[j]; idx[j] = tmp;
        }
      }
    }
  }
  __syncthreads();
  for (int k = tid; k < NNODE; k += 1024) {
    ss[(size_t)h * NNODE + k] = key[k];
    si[(size_t)h * NNODE + k] = idx[k];
  }
}

// zP[h][k] = sum_{r<k} e^{0.2 s_(r)}  (k in [0,4096]);  zS[h][k] = sum_{r>=k} e^{s_(r)}.
__global__ __launch_bounds__(256) void scanz_kernel(const float* __restrict__ ss,
                                                    float* __restrict__ zS,
                                                    float* __restrict__ zP) {
  __shared__ float tot[256];
  int h = blockIdx.x, t = threadIdx.x;
  int base = t * 16;
  size_t hb = (size_t)h * (NNODE + 1);
  float v[16];
  float lsum = 0.f;
  for (int q = 0; q < 16; q++) { v[q] = expf(NEG * ss[(size_t)h * NNODE + base + q]); lsum += v[q]; }
  tot[t] = lsum; __syncthreads();
  for (int off = 1; off < 256; off <<= 1) {
    float x = tot[t];
    float y = (t >= off) ? tot[t - off] : 0.f;
    __syncthreads();
    tot[t] = x + y; __syncthreads();
  }
  float run = (t > 0) ? tot[t - 1] : 0.f;
  for (int q = 0; q < 16; q++) { zP[hb + base + q] = run; run += v[q]; }
  if (t == 255) zP[hb + NNODE] = run;
  __syncthreads();
  lsum = 0.f;
  for (int q = 0; q < 16; q++) { v[q] = expf(ss[(size_t)h * NNODE + base + q]); lsum += v[q]; }
  tot[t] = lsum; __syncthreads();
  for (int off = 1; off < 256; off <<= 1) {
    float x = tot[t];
    float y = (t + off < 256) ? tot[t + off] : 0.f;
    __syncthreads();
    tot[t] = x + y; __syncthreads();
  }
  float run2 = (t < 255) ? tot[t + 1] : 0.f;
  for (int q = 15; q >= 0; q--) { run2 += v[q]; zS[hb + base + q] = run2; }
  if (t == 255) zS[hb + NNODE] = 0.f;
}

// Pass A: per-chunk partial sums of e^{s}*h (plus) and e^{0.2s}*h (minus).
__global__ __launch_bounds__(128) void passA_kernel(const float* __restrict__ h,
                                                    const float* __restrict__ ss,
                                                    const int* __restrict__ si,
                                                    float* __restrict__ partP,
                                                    float* __restrict__ partM, int H) {
  int b = blockIdx.x, hh = b / NCHUNK, ci = b % NCHUNK;
  int c = threadIdx.x;
  int HC = H * CDIM;
  int base = ci * CHUNK;
  float sp = 0.f, sm = 0.f;
  for (int kk = 0; kk < CHUNK; kk++) {
    int k = base + kk;
    float sv = ss[(size_t)hh * NNODE + k];
    int id = si[(size_t)hh * NNODE + k];
    float v = h[(size_t)id * HC + hh * CDIM + c];
    sp = fmaf(expf(sv), v, sp);
    sm = fmaf(expf(NEG * sv), v, sm);
  }
  partP[((size_t)hh * NCHUNK + ci) * CDIM + c] = sp;
  partM[((size_t)hh * NCHUNK + ci) * CDIM + c] = sm;
}

// Pass B: chunk carries (prefix for minus, suffix for plus).
__global__ __launch_bounds__(128) void passB_kernel(const float* __restrict__ partP,
                                                    const float* __restrict__ partM,
                                                    float* __restrict__ carryP,
                                                    float* __restrict__ carryM) {
  int hh = blockIdx.x, c = threadIdx.x;
  float run = 0.f;
  for (int ci = 0; ci < NCHUNK; ci++) {
    size_t o = ((size_t)hh * NCHUNK + ci) * CDIM + c;
    carryM[o] = run; run += partM[o];
  }
  run = 0.f;
  for (int ci = NCHUNK - 1; ci >= 0; ci--) {
    size_t o = ((size_t)hh * NCHUNK + ci) * CDIM + c;
    carryP[o] = run; run += partP[o];
  }
}

// Pass C: full tables. PP[k] = sum_{r<k} e^{0.2 s}h ; SS[k] = sum_{r>=k} e^{s}h.
__global__ __launch_bounds__(128) void passC_kernel(const float* __restrict__ h,
                                                    const float* __restrict__ ss,
                                                    const int* __restrict__ si,
                                                    const float* __restrict__ carryP,
                                                    const float* __restrict__ carryM,
                                                    float* __restrict__ SS,
                                                    float* __restrict__ PP, int H) {
  int b = blockIdx.x, hh = b / NCHUNK, ci = b % NCHUNK;
  int c = threadIdx.x;
  int HC = H * CDIM;
  int base = ci * CHUNK;
  size_t hb = (size_t)hh * (NNODE + 1);
  float run = carryM[((size_t)hh * NCHUNK + ci) * CDIM + c];
  for (int kk = 0; kk < CHUNK; kk++) {
    int k = base + kk;
    PP[(hb + k) * CDIM + c] = run;
    float sv = ss[(size_t)hh * NNODE + k];
    int id = si[(size_t)hh * NNODE + k];
    float v = h[(size_t)id * HC + hh * CDIM + c];
    run = fmaf(expf(NEG * sv), v, run);
  }
  if (ci == NCHUNK - 1) PP[(hb + NNODE) * CDIM + c] = run;
  run = carryP[((size_t)hh * NCHUNK + ci) * CDIM + c];
  for (int kk = CHUNK - 1; kk >= 0; kk--) {
    int k = base + kk;
    float sv = ss[(size_t)hh * NNODE + k];
    int id = si[(size_t)hh * NNODE + k];
    float v = h[(size_t)id * HC + hh * CDIM + c];
    run = fmaf(expf(sv), v, run);
    SS[(hb + k) * CDIM + c] = run;
  }
  if (ci == NCHUNK - 1) SS[(hb + NNODE) * CDIM + c] = 0.f;
}

// Per (dest, head): binary search split point, combine tables, +bias, ELU.
__global__ __launch_bounds__(128) void attend_kernel(const float* __restrict__ SS,
                                                     const float* __restrict__ PP,
                                                     const float* __restrict__ zS,
                                                     const float* __restrict__ zP,
                                                     const float* __restrict__ ss,
                                                     const float* __restrict__ tt,
                                                     const float* __restrict__ bias,
                                                     float* __restrict__ out, int H) {
  int b = blockIdx.x;
  int n = b / H, hh = b % H;
  int c = threadIdx.x;
  float tv = tt[(size_t)hh * NNODE + n];
  const float* sp = ss + (size_t)hh * NNODE;
  float thr = -tv;
  int lo = 0, hi = NNODE;
  while (lo < hi) { int mid = (lo + hi) >> 1; if (sp[mid] < thr) lo = mid + 1; else hi = mid; }
  size_t hb = (size_t)hh * (NNODE + 1);
  float wp = expf(tv), wm = expf(NEG * tv);
  float num = wp * SS[(hb + lo) * CDIM + c] + wm * PP[(hb + lo) * CDIM + c];
  float Z = wp * zS[hb + lo] + wm * zP[hb + lo];
  float o = num / Z + bias[hh * CDIM + c];
  out[(size_t)n * (H * CDIM) + hh * CDIM + c] = (o > 0.f) ? o : (expf(o) - 1.f);
}

__global__ __launch_bounds__(256) void mean_kernel(const float* __restrict__ x,
                                                   float* __restrict__ m) {
  __shared__ float red[256];
  int c = blockIdx.x, tid = threadIdx.x;
  float acc = 0.f;
  for (int i = tid; i < NNODE; i += 256) acc += x[(size_t)i * CDIM + c];
  red[tid] = acc; __syncthreads();
  for (int o = 128; o > 0; o >>= 1) { if (tid < o) red[tid] += red[tid + o]; __syncthreads(); }
  if (tid == 0) m[c] = red[0] * (1.f / NNODE);
}

__global__ __launch_bounds__(256) void fc_kernel(const float* __restrict__ m,
                                                 const float* __restrict__ fcW,
                                                 const float* __restrict__ fcb,
                                                 float* __restrict__ out) {
  int d = blockIdx.x * 256 + threadIdx.x;  // 768 total
  float acc = fcb[d];
  for (int c2 = 0; c2 < CDIM; c2++) acc = fmaf(m[c2], fcW[c2 * 768 + d], acc);
  out[d] = acc;
}

extern "C" void kernel_launch(void* const* d_in, const int* in_sizes, int n_in,
                              void* d_out, int out_size, void* d_ws, size_t ws_size,
                              hipStream_t stream) {
  const float* x   = (const float*)d_in[0];
  const float* W1  = (const float*)d_in[1];
  const float* as1 = (const float*)d_in[2];
  const float* ad1 = (const float*)d_in[3];
  const float* b1  = (const float*)d_in[4];
  const float* W2  = (const float*)d_in[5];
  const float* as2 = (const float*)d_in[6];
  const float* ad2 = (const float*)d_in[7];
  const float* b2  = (const float*)d_in[8];
  const float* fcW = (const float*)d_in[9];
  const float* fcb = (const float*)d_in[10];

  float* ws = (float*)d_ws;
  size_t off = 0;
  auto alloc = [&](size_t nfloats) { float* p = ws + off; off += nfloats; return p; };

  float* h1  = alloc((size_t)NNODE * 512);
  float* x2  = alloc((size_t)NNODE * 512);
  float* h2  = alloc((size_t)NNODE * 128);
  float* x3  = alloc((size_t)NNODE * 128);
  float* s1  = alloc((size_t)4 * NNODE);
  float* t1  = alloc((size_t)4 * NNODE);
  float* sS1 = alloc((size_t)4 * NNODE);
  int*   sI1 = (int*)alloc((size_t)4 * NNODE);
  float* SS1 = alloc((size_t)4 * (NNODE + 1) * 128);
  float* PP1 = alloc((size_t)4 * (NNODE + 1) * 128);
  float* zS1 = alloc((size_t)4 * (NNODE + 1));
  float* zP1 = alloc((size_t)4 * (NNODE + 1));
  float* pP1 = alloc((size_t)4 * NCHUNK * 128);
  float* pM1 = alloc((size_t)4 * NCHUNK * 128);
  float* cP1 = alloc((size_t)4 * NCHUNK * 128);
  float* cM1 = alloc((size_t)4 * NCHUNK * 128);
  float* s2  = alloc(NNODE);
  float* t2  = alloc(NNODE);
  float* sS2 = alloc(NNODE);
  int*   sI2 = (int*)alloc(NNODE);
  float* SS2 = alloc((size_t)(NNODE + 1) * 128);
  float* PP2 = alloc((size_t)(NNODE + 1) * 128);
  float* zS2 = alloc(NNODE + 1);
  float* zP2 = alloc(NNODE + 1);
  float* pP2 = alloc((size_t)NCHUNK * 128);
  float* pM2 = alloc((size_t)NCHUNK * 128);
  float* cP2 = alloc((size_t)NCHUNK * 128);
  float* cM2 = alloc((size_t)NCHUNK * 128);
  float* mv  = alloc(128);

  // Layer 1
  gemm_tile<<<dim3(512 / 64, NNODE / 64), 256, 0, stream>>>(x, W1, h1, NNODE, 512, 768);
  st_kernel<<<NNODE, 128, 0, stream>>>(h1, as1, ad1, s1, t1, 4);
  sort_kernel<<<4, 1024, 0, stream>>>(s1, sS1, sI1);
  scanz_kernel<<<4, 256, 0, stream>>>(sS1, zS1, zP1);
  passA_kernel<<<4 * NCHUNK, 128, 0, stream>>>(h1, sS1, sI1, pP1, pM1, 4);
  passB_kernel<<<4, 128, 0, stream>>>(pP1, pM1, cP1, cM1);
  passC_kernel<<<4 * NCHUNK, 128, 0, stream>>>(h1, sS1, sI1, cP1, cM1, SS1, PP1, 4);
  attend_kernel<<<NNODE * 4, 128, 0, stream>>>(SS1, PP1, zS1, zP1, sS1, t1, b1, x2, 4);
  // Layer 2
  gemm_tile<<<dim3(128 / 64, NNODE / 64), 256, 0, stream>>>(x2, W2, h2, NNODE, 128, 512);
  st_kernel<<<NNODE, 128, 0, stream>>>(h2, as2, ad2, s2, t2, 1);
  sort_kernel<<<1, 1024, 0, stream>>>(s2, sS2, sI2);
  scanz_kernel<<<1, 256, 0, stream>>>(sS2, zS2, zP2);
  passA_kernel<<<NCHUNK, 128, 0, stream>>>(h2, sS2, sI2, pP2, pM2, 1);
  passB_kernel<<<1, 128, 0, stream>>>(pP2, pM2, cP2, cM2);
  passC_kernel<<<NCHUNK, 128, 0, stream>>>(h2, sS2, sI2, cP2, cM2, SS2, PP2, 1);
  attend_kernel<<<NNODE, 128, 0, stream>>>(SS2, PP2, zS2, zP2, sS2, t2, b2, x3, 1);
  // Readout
  mean_kernel<<<128, 256, 0, stream>>>(x3, mv);
  fc_kernel<<<3, 256, 0, stream>>>(mv, fcW, fcb, (float*)d_out);
}

// Round 3
// 342.908 us; speedup vs baseline: 1.1200x; 1.1200x over previous
//
#include <hip/hip_runtime.h>
#include <hip/hip_bf16.h>

// FacePartGAT: dense-graph GATConv x2 + mean + fc on MI355X. ALL I/O fp32.
// Key trick: e[i,j] = leaky_relu(t_i + s_j) => softmax aggregation factorizes
// after sorting sources by s_j:
//   out_i = (e^{t_i} SS[k_i] + e^{0.2 t_i} PP[k_i]) / (e^{t_i} zS[k_i] + e^{0.2 t_i} zP[k_i])
// SS/PP suffix/prefix sums over sorted rank, k_i = lower_bound(sortedS, -t_i).
// Exact (reordered summation) — avoids the O(N^2 C) dense aggregation.
// Round 3: GEMM1 -> bf16 MFMA (16x16x32), inputs converted+B transposed first.

#define NNODE 4096
#define CDIM 128
#define NEG 0.2f
#define CHUNK 64
#define NCHUNK 64  // NNODE / CHUNK

typedef __bf16 bf16x8 __attribute__((ext_vector_type(8)));
typedef float f32x4 __attribute__((ext_vector_type(4)));

__device__ __forceinline__ unsigned short f2b(float f) {
  unsigned int u = __float_as_uint(f);
  u += 0x7fffu + ((u >> 16) & 1u);  // RTNE
  return (unsigned short)(u >> 16);
}

// fp32 -> bf16, 4 elems/thread.
__global__ __launch_bounds__(256) void convert_kernel(const float* __restrict__ in,
                                                      unsigned short* __restrict__ out,
                                                      int n4) {
  int i = blockIdx.x * 256 + threadIdx.x;
  if (i >= n4) return;
  float4 v = ((const float4*)in)[i];
  ushort4 o;
  o.x = f2b(v.x); o.y = f2b(v.y); o.z = f2b(v.z); o.w = f2b(v.w);
  ((ushort4*)out)[i] = o;
}

// W [K,N] fp32 -> Wt [N,K] bf16. 64x64 tiles, 256 threads.
__global__ __launch_bounds__(256) void transpose_convert_kernel(const float* __restrict__ W,
                                                                unsigned short* __restrict__ Wt,
                                                                int K, int N) {
  __shared__ float tile[64][65];
  int n0 = blockIdx.x * 64, k0 = blockIdx.y * 64;
  int t = threadIdx.x;
  for (int p = 0; p < 16; p++) {
    int e = p * 256 + t;
    int rr = e >> 6, cc = e & 63;
    tile[rr][cc] = W[(size_t)(k0 + rr) * N + n0 + cc];
  }
  __syncthreads();
  for (int p = 0; p < 16; p++) {
    int e = p * 256 + t;
    int rr = e >> 6, cc = e & 63;  // rr: n-dir, cc: k-dir
    Wt[(size_t)(n0 + rr) * K + k0 + cc] = f2b(tile[cc][rr]);
  }
}

// C[M,N] = A[M,K] x Bt[N,K]^T. bf16 in, fp32 out. BM=BN=128, BK=32.
// 256 thr = 4 waves (2x2 of 64x64), each wave 4x4 of 16x16x32 MFMA.
__global__ __launch_bounds__(256) void mfma_gemm_bt(const unsigned short* __restrict__ A,
                                                    const unsigned short* __restrict__ Bt,
                                                    float* __restrict__ C,
                                                    int M, int N, int K) {
  __shared__ __align__(16) unsigned short As[128 * 40];
  __shared__ __align__(16) unsigned short Bs[128 * 40];
  int tid = threadIdx.x;
  int lane = tid & 63, wave = tid >> 6;
  int wm = (wave >> 1) * 64, wn = (wave & 1) * 64;
  int m0 = blockIdx.y * 128, n0 = blockIdx.x * 128;
  int srow = tid >> 1;            // staging row 0..127
  int skoff = (tid & 1) * 16;     // staging k-offset 0/16
  int fm = lane & 15, fq = lane >> 4;  // fragment row/col, k-quad
  f32x4 acc[4][4] = {};
  for (int k0 = 0; k0 < K; k0 += 32) {
    const uint4* pa = (const uint4*)(A + (size_t)(m0 + srow) * K + k0 + skoff);
    uint4 a0 = pa[0], a1 = pa[1];
    const uint4* pb = (const uint4*)(Bt + (size_t)(n0 + srow) * K + k0 + skoff);
    uint4 b0 = pb[0], b1 = pb[1];
    __syncthreads();
    *(uint4*)&As[srow * 40 + skoff] = a0;
    *(uint4*)&As[srow * 40 + skoff + 8] = a1;
    *(uint4*)&Bs[srow * 40 + skoff] = b0;
    *(uint4*)&Bs[srow * 40 + skoff + 8] = b1;
    __syncthreads();
    bf16x8 af[4], bfr[4];
#pragma unroll
    for (int i = 0; i < 4; i++)
      af[i] = *(const bf16x8*)&As[(wm + i * 16 + fm) * 40 + fq * 8];
#pragma unroll
    for (int j = 0; j < 4; j++)
      bfr[j] = *(const bf16x8*)&Bs[(wn + j * 16 + fm) * 40 + fq * 8];
#pragma unroll
    for (int i = 0; i < 4; i++)
#pragma unroll
      for (int j = 0; j < 4; j++)
        acc[i][j] = __builtin_amdgcn_mfma_f32_16x16x32_bf16(af[i], bfr[j], acc[i][j], 0, 0, 0);
  }
#pragma unroll
  for (int i = 0; i < 4; i++) {
#pragma unroll
    for (int j = 0; j < 4; j++) {
      int r = m0 + wm + i * 16 + fq * 4;
      int ccol = n0 + wn + j * 16 + fm;
#pragma unroll
      for (int reg = 0; reg < 4; reg++)
        C[(size_t)(r + reg) * N + ccol] = acc[i][j][reg];
    }
  }
}

// C[M,Nn] = A[M,K] * B[K,Nn], all fp32. 64x64 tile, K-chunk 32, 256 thr, 4x4/thr.
__global__ __launch_bounds__(256) void gemm_tile(const float* __restrict__ A,
                                                 const float* __restrict__ B,
                                                 float* __restrict__ Cm,
                                                 int M, int Nn, int K) {
  __shared__ float As[32][65];
  __shared__ float Bs[32][65];
  int tid = threadIdx.x;
  int tx = tid & 15, ty = tid >> 4;
  int n0 = blockIdx.x * 64, m0 = blockIdx.y * 64;
  int am = tid >> 2, aq = tid & 3;
  int bk = tid >> 3, bc = tid & 7;
  float acc[4][4] = {};
  for (int k0 = 0; k0 < K; k0 += 32) {
    const float4* pa = (const float4*)(A + (size_t)(m0 + am) * K + k0 + aq * 8);
    float4 a0 = pa[0], a1 = pa[1];
    As[aq * 8 + 0][am] = a0.x; As[aq * 8 + 1][am] = a0.y;
    As[aq * 8 + 2][am] = a0.z; As[aq * 8 + 3][am] = a0.w;
    As[aq * 8 + 4][am] = a1.x; As[aq * 8 + 5][am] = a1.y;
    As[aq * 8 + 6][am] = a1.z; As[aq * 8 + 7][am] = a1.w;
    const float4* pb = (const float4*)(B + (size_t)(k0 + bk) * Nn + n0 + bc * 8);
    float4 b0 = pb[0], b1 = pb[1];
    Bs[bk][bc * 8 + 0] = b0.x; Bs[bk][bc * 8 + 1] = b0.y;
    Bs[bk][bc * 8 + 2] = b0.z; Bs[bk][bc * 8 + 3] = b0.w;
    Bs[bk][bc * 8 + 4] = b1.x; Bs[bk][bc * 8 + 5] = b1.y;
    Bs[bk][bc * 8 + 6] = b1.z; Bs[bk][bc * 8 + 7] = b1.w;
    __syncthreads();
#pragma unroll 8
    for (int kk = 0; kk < 32; kk++) {
      float av[4], bv[4];
#pragma unroll
      for (int i = 0; i < 4; i++) av[i] = As[kk][ty * 4 + i];
#pragma unroll
      for (int j = 0; j < 4; j++) bv[j] = Bs[kk][tx * 4 + j];
#pragma unroll
      for (int i = 0; i < 4; i++)
#pragma unroll
        for (int j = 0; j < 4; j++) acc[i][j] = fmaf(av[i], bv[j], acc[i][j]);
    }
    __syncthreads();
  }
#pragma unroll
  for (int i = 0; i < 4; i++)
#pragma unroll
    for (int j = 0; j < 4; j++)
      Cm[(size_t)(m0 + ty * 4 + i) * Nn + n0 + tx * 4 + j] = acc[i][j];
}

// s[h][n] = sum_c h[n, h*C+c] * att_src[h*C+c]; t likewise with att_dst.
__global__ __launch_bounds__(128) void st_kernel(const float* __restrict__ h,
                                                 const float* __restrict__ asrc,
                                                 const float* __restrict__ adst,
                                                 float* __restrict__ s, float* __restrict__ t,
                                                 int H) {
  __shared__ float red[128];
  int n = blockIdx.x, tid = threadIdx.x;
  int HC = H * CDIM;
  for (int hh = 0; hh < H; hh++) {
    float v = h[(size_t)n * HC + hh * CDIM + tid];
    float ps = v * asrc[hh * CDIM + tid];
    float pt = v * adst[hh * CDIM + tid];
    red[tid] = ps; __syncthreads();
    for (int o = 64; o > 0; o >>= 1) { if (tid < o) red[tid] += red[tid + o]; __syncthreads(); }
    if (tid == 0) s[(size_t)hh * NNODE + n] = red[0];
    __syncthreads();
    red[tid] = pt; __syncthreads();
    for (int o = 64; o > 0; o >>= 1) { if (tid < o) red[tid] += red[tid + o]; __syncthreads(); }
    if (tid == 0) t[(size_t)hh * NNODE + n] = red[0];
    __syncthreads();
  }
}

// Bitonic sort of 4096 (key,idx) pairs per head, ascending. One block per head.
__global__ __launch_bounds__(1024) void sort_kernel(const float* __restrict__ s,
                                                    float* __restrict__ ss,
                                                    int* __restrict__ si) {
  __shared__ float key[NNODE];
  __shared__ int idx[NNODE];
  int h = blockIdx.x, tid = threadIdx.x;
  for (int k = tid; k < NNODE; k += 1024) { key[k] = s[(size_t)h * NNODE + k]; idx[k] = k; }
  for (int size = 2; size <= NNODE; size <<= 1) {
    for (int stride = size >> 1; stride > 0; stride >>= 1) {
      __syncthreads();
      for (int t = tid; t < NNODE / 2; t += 1024) {
        int i = 2 * t - (t & (stride - 1));
        int j = i + stride;
        bool asc = ((i & size) == 0);
        float ki = key[i], kj = key[j];
        if ((ki > kj) == asc) {
          key[i] = kj; key[j] = ki;
          int tmp = idx[i]; idx[i] = idx[j]; idx[j] = tmp;
        }
      }
    }
  }
  __syncthreads();
  for (int k = tid; k < NNODE; k += 1024) {
    ss[(size_t)h * NNODE + k] = key[k];
    si[(size_t)h * NNODE + k] = idx[k];
  }
}

// zP[h][k] = sum_{r<k} e^{0.2 s_(r)}  (k in [0,4096]);  zS[h][k] = sum_{r>=k} e^{s_(r)}.
__global__ __launch_bounds__(256) void scanz_kernel(const float* __restrict__ ss,
                                                    float* __restrict__ zS,
                                                    float* __restrict__ zP) {
  __shared__ float tot[256];
  int h = blockIdx.x, t = threadIdx.x;
  int base = t * 16;
  size_t hb = (size_t)h * (NNODE + 1);
  float v[16];
  float lsum = 0.f;
  for (int q = 0; q < 16; q++) { v[q] = expf(NEG * ss[(size_t)h * NNODE + base + q]); lsum += v[q]; }
  tot[t] = lsum; __syncthreads();
  for (int off = 1; off < 256; off <<= 1) {
    float x = tot[t];
    float y = (t >= off) ? tot[t - off] : 0.f;
    __syncthreads();
    tot[t] = x + y; __syncthreads();
  }
  float run = (t > 0) ? tot[t - 1] : 0.f;
  for (int q = 0; q < 16; q++) { zP[hb + base + q] = run; run += v[q]; }
  if (t == 255) zP[hb + NNODE] = run;
  __syncthreads();
  lsum = 0.f;
  for (int q = 0; q < 16; q++) { v[q] = expf(ss[(size_t)h * NNODE + base + q]); lsum += v[q]; }
  tot[t] = lsum; __syncthreads();
  for (int off = 1; off < 256; off <<= 1) {
    float x = tot[t];
    float y = (t + off < 256) ? tot[t + off] : 0.f;
    __syncthreads();
    tot[t] = x + y; __syncthreads();
  }
  float run2 = (t < 255) ? tot[t + 1] : 0.f;
  for (int q = 15; q >= 0; q--) { run2 += v[q]; zS[hb + base + q] = run2; }
  if (t == 255) zS[hb + NNODE] = 0.f;
}

// Pass A: per-chunk partial sums of e^{s}*h (plus) and e^{0.2s}*h (minus).
__global__ __launch_bounds__(128) void passA_kernel(const float* __restrict__ h,
                                                    const float* __restrict__ ss,
                                                    const int* __restrict__ si,
                                                    float* __restrict__ partP,
                                                    float* __restrict__ partM, int H) {
  int b = blockIdx.x, hh = b / NCHUNK, ci = b % NCHUNK;
  int c = threadIdx.x;
  int HC = H * CDIM;
  int base = ci * CHUNK;
  float sp = 0.f, sm = 0.f;
  for (int kk = 0; kk < CHUNK; kk++) {
    int k = base + kk;
    float sv = ss[(size_t)hh * NNODE + k];
    int id = si[(size_t)hh * NNODE + k];
    float v = h[(size_t)id * HC + hh * CDIM + c];
    sp = fmaf(expf(sv), v, sp);
    sm = fmaf(expf(NEG * sv), v, sm);
  }
  partP[((size_t)hh * NCHUNK + ci) * CDIM + c] = sp;
  partM[((size_t)hh * NCHUNK + ci) * CDIM + c] = sm;
}

// Pass B: chunk carries (prefix for minus, suffix for plus).
__global__ __launch_bounds__(128) void passB_kernel(const float* __restrict__ partP,
                                                    const float* __restrict__ partM,
                                                    float* __restrict__ carryP,
                                                    float* __restrict__ carryM) {
  int hh = blockIdx.x, c = threadIdx.x;
  float run = 0.f;
  for (int ci = 0; ci < NCHUNK; ci++) {
    size_t o = ((size_t)hh * NCHUNK + ci) * CDIM + c;
    carryM[o] = run; run += partM[o];
  }
  run = 0.f;
  for (int ci = NCHUNK - 1; ci >= 0; ci--) {
    size_t o = ((size_t)hh * NCHUNK + ci) * CDIM + c;
    carryP[o] = run; run += partP[o];
  }
}

// Pass C: full tables. PP[k] = sum_{r<k} e^{0.2 s}h ; SS[k] = sum_{r>=k} e^{s}h.
__global__ __launch_bounds__(128) void passC_kernel(const float* __restrict__ h,
                                                    const float* __restrict__ ss,
                                                    const int* __restrict__ si,
                                                    const float* __restrict__ carryP,
                                                    const float* __restrict__ carryM,
                                                    float* __restrict__ SS,
                                                    float* __restrict__ PP, int H) {
  int b = blockIdx.x, hh = b / NCHUNK, ci = b % NCHUNK;
  int c = threadIdx.x;
  int HC = H * CDIM;
  int base = ci * CHUNK;
  size_t hb = (size_t)hh * (NNODE + 1);
  float run = carryM[((size_t)hh * NCHUNK + ci) * CDIM + c];
  for (int kk = 0; kk < CHUNK; kk++) {
    int k = base + kk;
    PP[(hb + k) * CDIM + c] = run;
    float sv = ss[(size_t)hh * NNODE + k];
    int id = si[(size_t)hh * NNODE + k];
    float v = h[(size_t)id * HC + hh * CDIM + c];
    run = fmaf(expf(NEG * sv), v, run);
  }
  if (ci == NCHUNK - 1) PP[(hb + NNODE) * CDIM + c] = run;
  run = carryP[((size_t)hh * NCHUNK + ci) * CDIM + c];
  for (int kk = CHUNK - 1; kk >= 0; kk--) {
    int k = base + kk;
    float sv = ss[(size_t)hh * NNODE + k];
    int id = si[(size_t)hh * NNODE + k];
    float v = h[(size_t)id * HC + hh * CDIM + c];
    run = fmaf(expf(sv), v, run);
    SS[(hb + k) * CDIM + c] = run;
  }
  if (ci == NCHUNK - 1) SS[(hb + NNODE) * CDIM + c] = 0.f;
}

// Per (dest, head): binary search split point, combine tables, +bias, ELU.
__global__ __launch_bounds__(128) void attend_kernel(const float* __restrict__ SS,
                                                     const float* __restrict__ PP,
                                                     const float* __restrict__ zS,
                                                     const float* __restrict__ zP,
                                                     const float* __restrict__ ss,
                                                     const float* __restrict__ tt,
                                                     const float* __restrict__ bias,
                                                     float* __restrict__ out, int H) {
  int b = blockIdx.x;
  int n = b / H, hh = b % H;
  int c = threadIdx.x;
  float tv = tt[(size_t)hh * NNODE + n];
  const float* sp = ss + (size_t)hh * NNODE;
  float thr = -tv;
  int lo = 0, hi = NNODE;
  while (lo < hi) { int mid = (lo + hi) >> 1; if (sp[mid] < thr) lo = mid + 1; else hi = mid; }
  size_t hb = (size_t)hh * (NNODE + 1);
  float wp = expf(tv), wm = expf(NEG * tv);
  float num = wp * SS[(hb + lo) * CDIM + c] + wm * PP[(hb + lo) * CDIM + c];
  float Z = wp * zS[hb + lo] + wm * zP[hb + lo];
  float o = num / Z + bias[hh * CDIM + c];
  out[(size_t)n * (H * CDIM) + hh * CDIM + c] = (o > 0.f) ? o : (expf(o) - 1.f);
}

__global__ __launch_bounds__(256) void mean_kernel(const float* __restrict__ x,
                                                   float* __restrict__ m) {
  __shared__ float red[256];
  int c = blockIdx.x, tid = threadIdx.x;
  float acc = 0.f;
  for (int i = tid; i < NNODE; i += 256) acc += x[(size_t)i * CDIM + c];
  red[tid] = acc; __syncthreads();
  for (int o = 128; o > 0; o >>= 1) { if (tid < o) red[tid] += red[tid + o]; __syncthreads(); }
  if (tid == 0) m[c] = red[0] * (1.f / NNODE);
}

__global__ __launch_bounds__(256) void fc_kernel(const float* __restrict__ m,
                                                 const float* __restrict__ fcW,
                                                 const float* __restrict__ fcb,
                                                 float* __restrict__ out) {
  int d = blockIdx.x * 256 + threadIdx.x;  // 768 total
  float acc = fcb[d];
  for (int c2 = 0; c2 < CDIM; c2++) acc = fmaf(m[c2], fcW[c2 * 768 + d], acc);
  out[d] = acc;
}

extern "C" void kernel_launch(void* const* d_in, const int* in_sizes, int n_in,
                              void* d_out, int out_size, void* d_ws, size_t ws_size,
                              hipStream_t stream) {
  const float* x   = (const float*)d_in[0];
  const float* W1  = (const float*)d_in[1];
  const float* as1 = (const float*)d_in[2];
  const float* ad1 = (const float*)d_in[3];
  const float* b1  = (const float*)d_in[4];
  const float* W2  = (const float*)d_in[5];
  const float* as2 = (const float*)d_in[6];
  const float* ad2 = (const float*)d_in[7];
  const float* b2  = (const float*)d_in[8];
  const float* fcW = (const float*)d_in[9];
  const float* fcb = (const float*)d_in[10];

  float* ws = (float*)d_ws;
  size_t off = 0;
  auto alloc = [&](size_t nfloats) { float* p = ws + off; off += nfloats; return p; };

  float* h1  = alloc((size_t)NNODE * 512);
  float* x2  = alloc((size_t)NNODE * 512);
  float* h2  = alloc((size_t)NNODE * 128);
  float* x3  = alloc((size_t)NNODE * 128);
  float* s1  = alloc((size_t)4 * NNODE);
  float* t1  = alloc((size_t)4 * NNODE);
  float* sS1 = alloc((size_t)4 * NNODE);
  int*   sI1 = (int*)alloc((size_t)4 * NNODE);
  float* SS1 = alloc((size_t)4 * (NNODE + 1) * 128);
  float* PP1 = alloc((size_t)4 * (NNODE + 1) * 128);
  float* zS1 = alloc((size_t)4 * (NNODE + 1));
  float* zP1 = alloc((size_t)4 * (NNODE + 1));
  float* pP1 = alloc((size_t)4 * NCHUNK * 128);
  float* pM1 = alloc((size_t)4 * NCHUNK * 128);
  float* cP1 = alloc((size_t)4 * NCHUNK * 128);
  float* cM1 = alloc((size_t)4 * NCHUNK * 128);
  float* s2  = alloc(NNODE);
  float* t2  = alloc(NNODE);
  float* sS2 = alloc(NNODE);
  int*   sI2 = (int*)alloc(NNODE);
  float* SS2 = alloc((size_t)(NNODE + 1) * 128);
  float* PP2 = alloc((size_t)(NNODE + 1) * 128);
  float* zS2 = alloc(NNODE + 1);
  float* zP2 = alloc(NNODE + 1);
  float* pP2 = alloc((size_t)NCHUNK * 128);
  float* pM2 = alloc((size_t)NCHUNK * 128);
  float* cP2 = alloc((size_t)NCHUNK * 128);
  float* cM2 = alloc((size_t)NCHUNK * 128);
  float* mv  = alloc(128);

  // bf16 staging buffers aliased into PP1/SS1 (first written in passC_kernel,
  // which runs strictly after mfma_gemm_bt completes — stream ordered).
  unsigned short* xb  = (unsigned short*)PP1;  // 4096x768 bf16 = 6.3 MB (< 8.4 MB)
  unsigned short* W1t = (unsigned short*)SS1;  // 512x768 bf16 = 0.79 MB

  // Layer 1
  convert_kernel<<<(NNODE * 768 / 4 + 255) / 256, 256, 0, stream>>>(x, xb, NNODE * 768 / 4);
  transpose_convert_kernel<<<dim3(512 / 64, 768 / 64), 256, 0, stream>>>(W1, W1t, 768, 512);
  mfma_gemm_bt<<<dim3(512 / 128, NNODE / 128), 256, 0, stream>>>(xb, W1t, h1, NNODE, 512, 768);
  st_kernel<<<NNODE, 128, 0, stream>>>(h1, as1, ad1, s1, t1, 4);
  sort_kernel<<<4, 1024, 0, stream>>>(s1, sS1, sI1);
  scanz_kernel<<<4, 256, 0, stream>>>(sS1, zS1, zP1);
  passA_kernel<<<4 * NCHUNK, 128, 0, stream>>>(h1, sS1, sI1, pP1, pM1, 4);
  passB_kernel<<<4, 128, 0, stream>>>(pP1, pM1, cP1, cM1);
  passC_kernel<<<4 * NCHUNK, 128, 0, stream>>>(h1, sS1, sI1, cP1, cM1, SS1, PP1, 4);
  attend_kernel<<<NNODE * 4, 128, 0, stream>>>(SS1, PP1, zS1, zP1, sS1, t1, b1, x2, 4);
  // Layer 2
  gemm_tile<<<dim3(128 / 64, NNODE / 64), 256, 0, stream>>>(x2, W2, h2, NNODE, 128, 512);
  st_kernel<<<NNODE, 128, 0, stream>>>(h2, as2, ad2, s2, t2, 1);
  sort_kernel<<<1, 1024, 0, stream>>>(s2, sS2, sI2);
  scanz_kernel<<<1, 256, 0, stream>>>(sS2, zS2, zP2);
  passA_kernel<<<NCHUNK, 128, 0, stream>>>(h2, sS2, sI2, pP2, pM2, 1);
  passB_kernel<<<1, 128, 0, stream>>>(pP2, pM2, cP2, cM2);
  passC_kernel<<<NCHUNK, 128, 0, stream>>>(h2, sS2, sI2, cP2, cM2, SS2, PP2, 1);
  attend_kernel<<<NNODE, 128, 0, stream>>>(SS2, PP2, zS2, zP2, sS2, t2, b2, x3, 1);
  // Readout
  mean_kernel<<<128, 256, 0, stream>>>(x3, mv);
  fc_kernel<<<3, 256, 0, stream>>>(mv, fcW, fcb, (float*)d_out);
}

// Round 4
// 265.575 us; speedup vs baseline: 1.4461x; 1.2912x over previous
//
#include <hip/hip_runtime.h>
#include <hip/hip_bf16.h>

// FacePartGAT: dense-graph GATConv x2 + mean + fc on MI355X. ALL I/O fp32.
// Key trick: e[i,j] = leaky_relu(t_i + s_j) => softmax aggregation factorizes
// after sorting sources by s_j:
//   out_i = (e^{t_i} SS[k_i] + e^{0.2 t_i} PP[k_i]) / (e^{t_i} zS[k_i] + e^{0.2 t_i} zP[k_i])
// SS/PP suffix/prefix sums over sorted rank, k_i = lower_bound(sortedS, -t_i).
// Exact (reordered summation) — avoids the O(N^2 C) dense aggregation.
// Round 4: bitonic sort -> segmented rank (counting) sort; GEMM2 -> bf16 MFMA;
//          st_kernel -> wave-shuffle reductions.

#define NNODE 4096
#define CDIM 128
#define NEG 0.2f
#define CHUNK 64
#define NCHUNK 64  // NNODE / CHUNK
#define SEG 8
#define SEGK (NNODE / SEG)  // 512

typedef __bf16 bf16x8 __attribute__((ext_vector_type(8)));
typedef float f32x4 __attribute__((ext_vector_type(4)));

__device__ __forceinline__ unsigned short f2b(float f) {
  unsigned int u = __float_as_uint(f);
  u += 0x7fffu + ((u >> 16) & 1u);  // RTNE
  return (unsigned short)(u >> 16);
}

// fp32 -> bf16, 4 elems/thread.
__global__ __launch_bounds__(256) void convert_kernel(const float* __restrict__ in,
                                                      unsigned short* __restrict__ out,
                                                      int n4) {
  int i = blockIdx.x * 256 + threadIdx.x;
  if (i >= n4) return;
  float4 v = ((const float4*)in)[i];
  ushort4 o;
  o.x = f2b(v.x); o.y = f2b(v.y); o.z = f2b(v.z); o.w = f2b(v.w);
  ((ushort4*)out)[i] = o;
}

// W [K,N] fp32 -> Wt [N,K] bf16. 64x64 tiles, 256 threads.
__global__ __launch_bounds__(256) void transpose_convert_kernel(const float* __restrict__ W,
                                                                unsigned short* __restrict__ Wt,
                                                                int K, int N) {
  __shared__ float tile[64][65];
  int n0 = blockIdx.x * 64, k0 = blockIdx.y * 64;
  int t = threadIdx.x;
  for (int p = 0; p < 16; p++) {
    int e = p * 256 + t;
    int rr = e >> 6, cc = e & 63;
    tile[rr][cc] = W[(size_t)(k0 + rr) * N + n0 + cc];
  }
  __syncthreads();
  for (int p = 0; p < 16; p++) {
    int e = p * 256 + t;
    int rr = e >> 6, cc = e & 63;  // rr: n-dir, cc: k-dir
    Wt[(size_t)(n0 + rr) * K + k0 + cc] = f2b(tile[cc][rr]);
  }
}

// C[M,N] = A[M,K] x Bt[N,K]^T. bf16 in, fp32 out. BM=BN=128, BK=32.
// 256 thr = 4 waves (2x2 of 64x64), each wave 4x4 of 16x16x32 MFMA.
__global__ __launch_bounds__(256) void mfma_gemm_bt(const unsigned short* __restrict__ A,
                                                    const unsigned short* __restrict__ Bt,
                                                    float* __restrict__ C,
                                                    int M, int N, int K) {
  __shared__ __align__(16) unsigned short As[128 * 40];
  __shared__ __align__(16) unsigned short Bs[128 * 40];
  int tid = threadIdx.x;
  int lane = tid & 63, wave = tid >> 6;
  int wm = (wave >> 1) * 64, wn = (wave & 1) * 64;
  int m0 = blockIdx.y * 128, n0 = blockIdx.x * 128;
  int srow = tid >> 1;            // staging row 0..127
  int skoff = (tid & 1) * 16;     // staging k-offset 0/16
  int fm = lane & 15, fq = lane >> 4;  // fragment row/col, k-quad
  f32x4 acc[4][4] = {};
  for (int k0 = 0; k0 < K; k0 += 32) {
    const uint4* pa = (const uint4*)(A + (size_t)(m0 + srow) * K + k0 + skoff);
    uint4 a0 = pa[0], a1 = pa[1];
    const uint4* pb = (const uint4*)(Bt + (size_t)(n0 + srow) * K + k0 + skoff);
    uint4 b0 = pb[0], b1 = pb[1];
    __syncthreads();
    *(uint4*)&As[srow * 40 + skoff] = a0;
    *(uint4*)&As[srow * 40 + skoff + 8] = a1;
    *(uint4*)&Bs[srow * 40 + skoff] = b0;
    *(uint4*)&Bs[srow * 40 + skoff + 8] = b1;
    __syncthreads();
    bf16x8 af[4], bfr[4];
#pragma unroll
    for (int i = 0; i < 4; i++)
      af[i] = *(const bf16x8*)&As[(wm + i * 16 + fm) * 40 + fq * 8];
#pragma unroll
    for (int j = 0; j < 4; j++)
      bfr[j] = *(const bf16x8*)&Bs[(wn + j * 16 + fm) * 40 + fq * 8];
#pragma unroll
    for (int i = 0; i < 4; i++)
#pragma unroll
      for (int j = 0; j < 4; j++)
        acc[i][j] = __builtin_amdgcn_mfma_f32_16x16x32_bf16(af[i], bfr[j], acc[i][j], 0, 0, 0);
  }
#pragma unroll
  for (int i = 0; i < 4; i++) {
#pragma unroll
    for (int j = 0; j < 4; j++) {
      int r = m0 + wm + i * 16 + fq * 4;
      int ccol = n0 + wn + j * 16 + fm;
#pragma unroll
      for (int reg = 0; reg < 4; reg++)
        C[(size_t)(r + reg) * N + ccol] = acc[i][j][reg];
    }
  }
}

// s[h][n], t[h][n] via one wave per (node, head); shuffle reduce, no LDS.
__global__ void st_kernel(const float* __restrict__ h,
                          const float* __restrict__ asrc,
                          const float* __restrict__ adst,
                          float* __restrict__ s, float* __restrict__ t, int H) {
  int n = blockIdx.x;
  int wave = threadIdx.x >> 6, lane = threadIdx.x & 63;
  int HC = H * CDIM;
  float2 hv = *(const float2*)&h[(size_t)n * HC + wave * CDIM + lane * 2];
  float2 av = *(const float2*)&asrc[wave * CDIM + lane * 2];
  float2 dv = *(const float2*)&adst[wave * CDIM + lane * 2];
  float ps = hv.x * av.x + hv.y * av.y;
  float pt = hv.x * dv.x + hv.y * dv.y;
#pragma unroll
  for (int o = 32; o > 0; o >>= 1) {
    ps += __shfl_down(ps, o, 64);
    pt += __shfl_down(pt, o, 64);
  }
  if (lane == 0) {
    s[(size_t)wave * NNODE + n] = ps;
    t[(size_t)wave * NNODE + n] = pt;
  }
}

// Segmented rank sort, pass 1: partial rank counts over a 512-key segment.
// grid (NNODE/256, SEG, H). rank_i = #{j: kj<ki || (kj==ki && j<i)} — exact perm.
__global__ __launch_bounds__(256) void rank_count_kernel(const float* __restrict__ s,
                                                         int* __restrict__ partial) {
  __shared__ __align__(16) float keys[SEGK];
  int hh = blockIdx.z, seg = blockIdx.y, tid = threadIdx.x;
  const float* sp = s + (size_t)hh * NNODE;
  for (int k = tid; k < SEGK; k += 256) keys[k] = sp[seg * SEGK + k];
  __syncthreads();
  int mi = blockIdx.x * 256 + tid;
  float mk = sp[mi];
  int jbase = seg * SEGK;
  int cnt = 0;
#pragma unroll 4
  for (int j = 0; j < SEGK; j += 4) {
    float4 kv = *(const float4*)&keys[j];
    int jj = jbase + j;
    cnt += (kv.x < mk) || (kv.x == mk && (jj + 0) < mi);
    cnt += (kv.y < mk) || (kv.y == mk && (jj + 1) < mi);
    cnt += (kv.z < mk) || (kv.z == mk && (jj + 2) < mi);
    cnt += (kv.w < mk) || (kv.w == mk && (jj + 3) < mi);
  }
  partial[((size_t)hh * SEG + seg) * NNODE + mi] = cnt;
}

// Pass 2: combine partials, scatter keys+indices to sorted position.
__global__ __launch_bounds__(256) void rank_scatter_kernel(const float* __restrict__ s,
                                                           const int* __restrict__ partial,
                                                           float* __restrict__ ss,
                                                           int* __restrict__ si) {
  int hh = blockIdx.y;
  int mi = blockIdx.x * 256 + threadIdx.x;
  int rank = 0;
#pragma unroll
  for (int g = 0; g < SEG; g++) rank += partial[((size_t)hh * SEG + g) * NNODE + mi];
  float mk = s[(size_t)hh * NNODE + mi];
  ss[(size_t)hh * NNODE + rank] = mk;
  si[(size_t)hh * NNODE + rank] = mi;
}

// zP[h][k] = sum_{r<k} e^{0.2 s_(r)}  (k in [0,4096]);  zS[h][k] = sum_{r>=k} e^{s_(r)}.
__global__ __launch_bounds__(256) void scanz_kernel(const float* __restrict__ ss,
                                                    float* __restrict__ zS,
                                                    float* __restrict__ zP) {
  __shared__ float tot[256];
  int h = blockIdx.x, t = threadIdx.x;
  int base = t * 16;
  size_t hb = (size_t)h * (NNODE + 1);
  float v[16];
  float lsum = 0.f;
  for (int q = 0; q < 16; q++) { v[q] = expf(NEG * ss[(size_t)h * NNODE + base + q]); lsum += v[q]; }
  tot[t] = lsum; __syncthreads();
  for (int off = 1; off < 256; off <<= 1) {
    float x = tot[t];
    float y = (t >= off) ? tot[t - off] : 0.f;
    __syncthreads();
    tot[t] = x + y; __syncthreads();
  }
  float run = (t > 0) ? tot[t - 1] : 0.f;
  for (int q = 0; q < 16; q++) { zP[hb + base + q] = run; run += v[q]; }
  if (t == 255) zP[hb + NNODE] = run;
  __syncthreads();
  lsum = 0.f;
  for (int q = 0; q < 16; q++) { v[q] = expf(ss[(size_t)h * NNODE + base + q]); lsum += v[q]; }
  tot[t] = lsum; __syncthreads();
  for (int off = 1; off < 256; off <<= 1) {
    float x = tot[t];
    float y = (t + off < 256) ? tot[t + off] : 0.f;
    __syncthreads();
    tot[t] = x + y; __syncthreads();
  }
  float run2 = (t < 255) ? tot[t + 1] : 0.f;
  for (int q = 15; q >= 0; q--) { run2 += v[q]; zS[hb + base + q] = run2; }
  if (t == 255) zS[hb + NNODE] = 0.f;
}

// Pass A: per-chunk partial sums of e^{s}*h (plus) and e^{0.2s}*h (minus).
__global__ __launch_bounds__(128) void passA_kernel(const float* __restrict__ h,
                                                    const float* __restrict__ ss,
                                                    const int* __restrict__ si,
                                                    float* __restrict__ partP,
                                                    float* __restrict__ partM, int H) {
  int b = blockIdx.x, hh = b / NCHUNK, ci = b % NCHUNK;
  int c = threadIdx.x;
  int HC = H * CDIM;
  int base = ci * CHUNK;
  float sp = 0.f, sm = 0.f;
  for (int kk = 0; kk < CHUNK; kk++) {
    int k = base + kk;
    float sv = ss[(size_t)hh * NNODE + k];
    int id = si[(size_t)hh * NNODE + k];
    float v = h[(size_t)id * HC + hh * CDIM + c];
    sp = fmaf(expf(sv), v, sp);
    sm = fmaf(expf(NEG * sv), v, sm);
  }
  partP[((size_t)hh * NCHUNK + ci) * CDIM + c] = sp;
  partM[((size_t)hh * NCHUNK + ci) * CDIM + c] = sm;
}

// Pass B: chunk carries (prefix for minus, suffix for plus).
__global__ __launch_bounds__(128) void passB_kernel(const float* __restrict__ partP,
                                                    const float* __restrict__ partM,
                                                    float* __restrict__ carryP,
                                                    float* __restrict__ carryM) {
  int hh = blockIdx.x, c = threadIdx.x;
  float run = 0.f;
  for (int ci = 0; ci < NCHUNK; ci++) {
    size_t o = ((size_t)hh * NCHUNK + ci) * CDIM + c;
    carryM[o] = run; run += partM[o];
  }
  run = 0.f;
  for (int ci = NCHUNK - 1; ci >= 0; ci--) {
    size_t o = ((size_t)hh * NCHUNK + ci) * CDIM + c;
    carryP[o] = run; run += partP[o];
  }
}

// Pass C: full tables. PP[k] = sum_{r<k} e^{0.2 s}h ; SS[k] = sum_{r>=k} e^{s}h.
__global__ __launch_bounds__(128) void passC_kernel(const float* __restrict__ h,
                                                    const float* __restrict__ ss,
                                                    const int* __restrict__ si,
                                                    const float* __restrict__ carryP,
                                                    const float* __restrict__ carryM,
                                                    float* __restrict__ SS,
                                                    float* __restrict__ PP, int H) {
  int b = blockIdx.x, hh = b / NCHUNK, ci = b % NCHUNK;
  int c = threadIdx.x;
  int HC = H * CDIM;
  int base = ci * CHUNK;
  size_t hb = (size_t)hh * (NNODE + 1);
  float run = carryM[((size_t)hh * NCHUNK + ci) * CDIM + c];
  for (int kk = 0; kk < CHUNK; kk++) {
    int k = base + kk;
    PP[(hb + k) * CDIM + c] = run;
    float sv = ss[(size_t)hh * NNODE + k];
    int id = si[(size_t)hh * NNODE + k];
    float v = h[(size_t)id * HC + hh * CDIM + c];
    run = fmaf(expf(NEG * sv), v, run);
  }
  if (ci == NCHUNK - 1) PP[(hb + NNODE) * CDIM + c] = run;
  run = carryP[((size_t)hh * NCHUNK + ci) * CDIM + c];
  for (int kk = CHUNK - 1; kk >= 0; kk--) {
    int k = base + kk;
    float sv = ss[(size_t)hh * NNODE + k];
    int id = si[(size_t)hh * NNODE + k];
    float v = h[(size_t)id * HC + hh * CDIM + c];
    run = fmaf(expf(sv), v, run);
    SS[(hb + k) * CDIM + c] = run;
  }
  if (ci == NCHUNK - 1) SS[(hb + NNODE) * CDIM + c] = 0.f;
}

// Per (dest, head): binary search split point, combine tables, +bias, ELU.
// OUT = unsigned short (bf16, for layer-1 -> MFMA GEMM2 input) or float.
template <typename OUT>
__global__ __launch_bounds__(128) void attend_kernel(const float* __restrict__ SS,
                                                     const float* __restrict__ PP,
                                                     const float* __restrict__ zS,
                                                     const float* __restrict__ zP,
                                                     const float* __restrict__ ss,
                                                     const float* __restrict__ tt,
                                                     const float* __restrict__ bias,
                                                     OUT* __restrict__ out, int H) {
  int b = blockIdx.x;
  int n = b / H, hh = b % H;
  int c = threadIdx.x;
  float tv = tt[(size_t)hh * NNODE + n];
  const float* sp = ss + (size_t)hh * NNODE;
  float thr = -tv;
  int lo = 0, hi = NNODE;
  while (lo < hi) { int mid = (lo + hi) >> 1; if (sp[mid] < thr) lo = mid + 1; else hi = mid; }
  size_t hb = (size_t)hh * (NNODE + 1);
  float wp = expf(tv), wm = expf(NEG * tv);
  float num = wp * SS[(hb + lo) * CDIM + c] + wm * PP[(hb + lo) * CDIM + c];
  float Z = wp * zS[hb + lo] + wm * zP[hb + lo];
  float o = num / Z + bias[hh * CDIM + c];
  float r = (o > 0.f) ? o : (expf(o) - 1.f);
  if constexpr (sizeof(OUT) == 2)
    out[(size_t)n * (H * CDIM) + hh * CDIM + c] = f2b(r);
  else
    out[(size_t)n * (H * CDIM) + hh * CDIM + c] = r;
}

__global__ __launch_bounds__(256) void mean_kernel(const float* __restrict__ x,
                                                   float* __restrict__ m) {
  __shared__ float red[256];
  int c = blockIdx.x, tid = threadIdx.x;
  float acc = 0.f;
  for (int i = tid; i < NNODE; i += 256) acc += x[(size_t)i * CDIM + c];
  red[tid] = acc; __syncthreads();
  for (int o = 128; o > 0; o >>= 1) { if (tid < o) red[tid] += red[tid + o]; __syncthreads(); }
  if (tid == 0) m[c] = red[0] * (1.f / NNODE);
}

__global__ __launch_bounds__(256) void fc_kernel(const float* __restrict__ m,
                                                 const float* __restrict__ fcW,
                                                 const float* __restrict__ fcb,
                                                 float* __restrict__ out) {
  int d = blockIdx.x * 256 + threadIdx.x;  // 768 total
  float acc = fcb[d];
  for (int c2 = 0; c2 < CDIM; c2++) acc = fmaf(m[c2], fcW[c2 * 768 + d], acc);
  out[d] = acc;
}

extern "C" void kernel_launch(void* const* d_in, const int* in_sizes, int n_in,
                              void* d_out, int out_size, void* d_ws, size_t ws_size,
                              hipStream_t stream) {
  const float* x   = (const float*)d_in[0];
  const float* W1  = (const float*)d_in[1];
  const float* as1 = (const float*)d_in[2];
  const float* ad1 = (const float*)d_in[3];
  const float* b1  = (const float*)d_in[4];
  const float* W2  = (const float*)d_in[5];
  const float* as2 = (const float*)d_in[6];
  const float* ad2 = (const float*)d_in[7];
  const float* b2  = (const float*)d_in[8];
  const float* fcW = (const float*)d_in[9];
  const float* fcb = (const float*)d_in[10];

  float* ws = (float*)d_ws;
  size_t off = 0;
  auto alloc = [&](size_t nfloats) { float* p = ws + off; off += nfloats; return p; };

  float* h1  = alloc((size_t)NNODE * 512);
  float* x2f = alloc((size_t)NNODE * 512);   // first 4096x512 bf16 = x2b; tail = W2t
  float* h2  = alloc((size_t)NNODE * 128);
  float* x3  = alloc((size_t)NNODE * 128);
  float* s1  = alloc((size_t)4 * NNODE);
  float* t1  = alloc((size_t)4 * NNODE);
  float* sS1 = alloc((size_t)4 * NNODE);
  int*   sI1 = (int*)alloc((size_t)4 * NNODE);
  float* SS1 = alloc((size_t)4 * (NNODE + 1) * 128);
  float* PP1 = alloc((size_t)4 * (NNODE + 1) * 128);
  float* zS1 = alloc((size_t)4 * (NNODE + 1));
  float* zP1 = alloc((size_t)4 * (NNODE + 1));
  float* pP1 = alloc((size_t)4 * NCHUNK * 128);
  float* pM1 = alloc((size_t)4 * NCHUNK * 128);
  float* cP1 = alloc((size_t)4 * NCHUNK * 128);
  float* cM1 = alloc((size_t)4 * NCHUNK * 128);
  float* s2  = alloc(NNODE);
  float* t2  = alloc(NNODE);
  float* sS2 = alloc(NNODE);
  int*   sI2 = (int*)alloc(NNODE);
  float* SS2 = alloc((size_t)(NNODE + 1) * 128);
  float* PP2 = alloc((size_t)(NNODE + 1) * 128);
  float* zS2 = alloc(NNODE + 1);
  float* zP2 = alloc(NNODE + 1);
  float* pP2 = alloc((size_t)NCHUNK * 128);
  float* pM2 = alloc((size_t)NCHUNK * 128);
  float* cP2 = alloc((size_t)NCHUNK * 128);
  float* cM2 = alloc((size_t)NCHUNK * 128);
  float* mv  = alloc(128);
  int*   rparts = (int*)alloc((size_t)4 * SEG * NNODE);  // rank partials (512 KB)

  // bf16 staging buffers aliased into PP1/SS1 (first written in passC_kernel,
  // which runs strictly after mfma_gemm_bt completes — stream ordered).
  unsigned short* xb  = (unsigned short*)PP1;  // 4096x768 bf16 = 6.3 MB
  unsigned short* W1t = (unsigned short*)SS1;  // 512x768 bf16
  unsigned short* x2b = (unsigned short*)x2f;                    // 4096x512 bf16 = 4 MB
  unsigned short* W2t = (unsigned short*)(x2f + NNODE * 256 + 64);  // 128x512 bf16

  // Layer 1
  convert_kernel<<<(NNODE * 768 / 4 + 255) / 256, 256, 0, stream>>>(x, xb, NNODE * 768 / 4);
  transpose_convert_kernel<<<dim3(512 / 64, 768 / 64), 256, 0, stream>>>(W1, W1t, 768, 512);
  mfma_gemm_bt<<<dim3(512 / 128, NNODE / 128), 256, 0, stream>>>(xb, W1t, h1, NNODE, 512, 768);
  st_kernel<<<NNODE, 4 * 64, 0, stream>>>(h1, as1, ad1, s1, t1, 4);
  rank_count_kernel<<<dim3(NNODE / 256, SEG, 4), 256, 0, stream>>>(s1, rparts);
  rank_scatter_kernel<<<dim3(NNODE / 256, 4), 256, 0, stream>>>(s1, rparts, sS1, sI1);
  scanz_kernel<<<4, 256, 0, stream>>>(sS1, zS1, zP1);
  passA_kernel<<<4 * NCHUNK, 128, 0, stream>>>(h1, sS1, sI1, pP1, pM1, 4);
  passB_kernel<<<4, 128, 0, stream>>>(pP1, pM1, cP1, cM1);
  passC_kernel<<<4 * NCHUNK, 128, 0, stream>>>(h1, sS1, sI1, cP1, cM1, SS1, PP1, 4);
  attend_kernel<unsigned short><<<NNODE * 4, 128, 0, stream>>>(SS1, PP1, zS1, zP1, sS1, t1, b1, x2b, 4);
  // Layer 2 (GEMM on matrix cores: x2b [4096,512] bf16 x W2t [128,512]^T)
  transpose_convert_kernel<<<dim3(128 / 64, 512 / 64), 256, 0, stream>>>(W2, W2t, 512, 128);
  mfma_gemm_bt<<<dim3(128 / 128, NNODE / 128), 256, 0, stream>>>(x2b, W2t, h2, NNODE, 128, 512);
  st_kernel<<<NNODE, 1 * 64, 0, stream>>>(h2, as2, ad2, s2, t2, 1);
  rank_count_kernel<<<dim3(NNODE / 256, SEG, 1), 256, 0, stream>>>(s2, rparts);
  rank_scatter_kernel<<<dim3(NNODE / 256, 1), 256, 0, stream>>>(s2, rparts, sS2, sI2);
  scanz_kernel<<<1, 256, 0, stream>>>(sS2, zS2, zP2);
  passA_kernel<<<NCHUNK, 128, 0, stream>>>(h2, sS2, sI2, pP2, pM2, 1);
  passB_kernel<<<1, 128, 0, stream>>>(pP2, pM2, cP2, cM2);
  passC_kernel<<<NCHUNK, 128, 0, stream>>>(h2, sS2, sI2, cP2, cM2, SS2, PP2, 1);
  attend_kernel<float><<<NNODE, 128, 0, stream>>>(SS2, PP2, zS2, zP2, sS2, t2, b2, x3, 1);
  // Readout
  mean_kernel<<<128, 256, 0, stream>>>(x3, mv);
  fc_kernel<<<3, 256, 0, stream>>>(mv, fcW, fcb, (float*)d_out);
}